// Round 1
// baseline (333.901 us; speedup 1.0000x reference)
//
#include <hip/hip_runtime.h>

// Sinkhorn OT, scaling form (no log/exp in the loop):
//   K = exp(-C/eps); s0 = 1
//   repeat 40x: r = (1/M) ./ (K s);  s = (1/N) ./ (K^T r)
//   P = diag(r) K diag(s); dist_b = sum(P .* C)
// B=4, M=N=1024, fp32. Output: dist (B floats) then P (B*M*N floats).

#define MN 1024
#define EPS_INV 10.0f

// ---------------- init: s = 1 ----------------
__global__ __launch_bounds__(256) void init_s(float* __restrict__ s, int n) {
    int i = blockIdx.x * 256 + threadIdx.x;
    if (i < n) s[i] = 1.0f;
}

// ---------------- build K = exp(-10*C) and K^T (tiled transpose) ----------------
// grid: (MN/64, MN/64, B), block: 256
__global__ __launch_bounds__(256) void build_K(const float* __restrict__ C,
                                               float* __restrict__ K,
                                               float* __restrict__ KT) {
    __shared__ float tile[64][65];  // +1 pad: conflict-free transpose read
    const int b  = blockIdx.z;
    const int tr = blockIdx.y * 64;  // tile row origin
    const int tc = blockIdx.x * 64;  // tile col origin
    const size_t base = (size_t)b * MN * MN;
    const int tx = threadIdx.x & 63;   // 0..63
    const int ty = threadIdx.x >> 6;   // 0..3

#pragma unroll
    for (int stp = 0; stp < 16; ++stp) {
        int row = ty + stp * 4;
        size_t idx = base + (size_t)(tr + row) * MN + tc + tx;
        float k = expf(-EPS_INV * C[idx]);   // one-time: precise expf
        K[idx] = k;
        tile[row][tx] = k;
    }
    __syncthreads();
#pragma unroll
    for (int stp = 0; stp < 16; ++stp) {
        int col = ty + stp * 4;
        // KT[n, m] = K[m, n]
        KT[base + (size_t)(tc + col) * MN + tr + tx] = tile[tx][col];
    }
}

// ---------------- GEMV + reciprocal: vout[row] = invsize / dot(Mtx[row,:], vin_b) ----------
// one wave per row; 4 waves (4 rows) per block; rows within a block share a batch
// grid: B*MN/4 blocks, 256 threads
__global__ __launch_bounds__(256) void gemv_recip(const float* __restrict__ Mtx,
                                                  const float* __restrict__ vin,
                                                  float* __restrict__ vout,
                                                  float invsize) {
    const int row  = blockIdx.x * 4 + (threadIdx.x >> 6);
    const int lane = threadIdx.x & 63;
    const int b    = row >> 10;  // row / 1024
    const float* __restrict__ mrow = Mtx + (size_t)row * MN;
    const float* __restrict__ vb   = vin + ((size_t)b << 10);

    float acc = 0.f;
#pragma unroll
    for (int c = 0; c < 4; ++c) {
        int idx = c * 256 + lane * 4;
        float4 k4 = *(const float4*)(mrow + idx);
        float4 v4 = *(const float4*)(vb + idx);
        acc += k4.x * v4.x + k4.y * v4.y + k4.z * v4.z + k4.w * v4.w;
    }
#pragma unroll
    for (int off = 32; off; off >>= 1) acc += __shfl_xor(acc, off, 64);
    if (lane == 0) vout[row] = invsize / acc;
}

// ---------------- finalize: P = r K s, per-block partial of sum(P.*C) ----------------
// same row mapping as gemv_recip; partial[blockIdx.x] written for later reduction
__global__ __launch_bounds__(256) void finalize(const float* __restrict__ K,
                                                const float* __restrict__ C,
                                                const float* __restrict__ r,
                                                const float* __restrict__ s,
                                                float* __restrict__ P,
                                                float* __restrict__ partial) {
    const int row  = blockIdx.x * 4 + (threadIdx.x >> 6);
    const int lane = threadIdx.x & 63;
    const int b    = row >> 10;
    const float rm = r[row];
    const float* __restrict__ kr = K + (size_t)row * MN;
    const float* __restrict__ cr = C + (size_t)row * MN;
    const float* __restrict__ sb = s + ((size_t)b << 10);
    float* __restrict__ pr = P + (size_t)row * MN;

    float acc = 0.f;
#pragma unroll
    for (int c = 0; c < 4; ++c) {
        int idx = c * 256 + lane * 4;
        float4 k4 = *(const float4*)(kr + idx);
        float4 c4 = *(const float4*)(cr + idx);
        float4 s4 = *(const float4*)(sb + idx);
        float4 p4;
        p4.x = rm * k4.x * s4.x;
        p4.y = rm * k4.y * s4.y;
        p4.z = rm * k4.z * s4.z;
        p4.w = rm * k4.w * s4.w;
        *(float4*)(pr + idx) = p4;
        acc += p4.x * c4.x + p4.y * c4.y + p4.z * c4.z + p4.w * c4.w;
    }
#pragma unroll
    for (int off = 32; off; off >>= 1) acc += __shfl_xor(acc, off, 64);
    __shared__ float wsum[4];
    if (lane == 0) wsum[threadIdx.x >> 6] = acc;
    __syncthreads();
    if (threadIdx.x == 0)
        partial[blockIdx.x] = wsum[0] + wsum[1] + wsum[2] + wsum[3];
}

// ---------------- reduce 256 partials per batch into dist[b] ----------------
// grid: B blocks, 256 threads (256 row-blocks per batch, contiguous)
__global__ __launch_bounds__(256) void sum_dist(const float* __restrict__ partial,
                                                float* __restrict__ dist) {
    float v = partial[blockIdx.x * 256 + threadIdx.x];
#pragma unroll
    for (int off = 32; off; off >>= 1) v += __shfl_xor(v, off, 64);
    __shared__ float wsum[4];
    if ((threadIdx.x & 63) == 0) wsum[threadIdx.x >> 6] = v;
    __syncthreads();
    if (threadIdx.x == 0) dist[blockIdx.x] = wsum[0] + wsum[1] + wsum[2] + wsum[3];
}

extern "C" void kernel_launch(void* const* d_in, const int* in_sizes, int n_in,
                              void* d_out, int out_size, void* d_ws, size_t ws_size,
                              hipStream_t stream) {
    const float* C = (const float*)d_in[0];
    const int B = in_sizes[0] / (MN * MN);  // 4

    // ws layout (floats): K [B*MN*MN] | KT [B*MN*MN] | r [B*MN] | s [B*MN] | partial [B*MN/4]
    float* ws = (float*)d_ws;
    float* K  = ws;
    float* KT = ws + (size_t)B * MN * MN;
    float* r  = ws + (size_t)2 * B * MN * MN;
    float* s  = r + (size_t)B * MN;
    float* partial = s + (size_t)B * MN;

    float* dist = (float*)d_out;       // (B,)
    float* P    = (float*)d_out + B;   // (B, MN, MN)

    const int rowBlocks = B * MN / 4;  // 1024
    const float inv = 1.0f / (float)MN;

    init_s<<<(B * MN + 255) / 256, 256, 0, stream>>>(s, B * MN);
    build_K<<<dim3(MN / 64, MN / 64, B), 256, 0, stream>>>(C, K, KT);

    for (int it = 0; it < 40; ++it) {
        gemv_recip<<<rowBlocks, 256, 0, stream>>>(K, s, r, inv);   // u-update
        gemv_recip<<<rowBlocks, 256, 0, stream>>>(KT, r, s, inv);  // v-update
    }

    finalize<<<rowBlocks, 256, 0, stream>>>(K, C, r, s, P, partial);
    sum_dist<<<B, 256, 0, stream>>>(partial, dist);
}